// Round 10
// baseline (199.819 us; speedup 1.0000x reference)
//
#include <hip/hip_runtime.h>
#include <math.h>

typedef unsigned short ushort;
typedef unsigned int uint;
typedef unsigned char uchar;

#define B 4
#define C 64
#define H 64
#define W 64
#define HW 4096
#define NEG 256
#define CHUNK_P 8
#define NCHUNK (HW / CHUNK_P)   // 512
#define NGRP 16
#define NBLK (B * NCHUNK)       // 2048

#define QS 7.49f
#define INVQS2 (1.0f / (QS * QS))
#define RGBNORM 2.26410874e-3f   // 1/(255*sqrt(3))

// ---------------- ws layout (float units) ----------------
// z2i4   : [B][HW][32B] int4 (column pre-normalized, xQS) = B*HW*8 floats
// n1map  : [B][HW]
// imgu8  : [HW] uint (packed u8 r,g,b)
// partial2:[B][NGRP][NEG]  (atomically accumulated; zeroed by k_prep)
// cnt    : 1 uint completion counter (zeroed by k_prep)
#define OFF_Z2T     0
#define OFF_N1MAP   (OFF_Z2T + B*HW*8)
#define OFF_IMGU8   (OFF_N1MAP + B*HW)
#define OFF_PART2   (OFF_IMGU8 + HW)
#define OFF_CNT     (OFF_PART2 + B*NGRP*NEG)

__device__ __forceinline__ int nib(uint u, int j) {
    return ((int)(u << (28 - 4 * j))) >> 28;
}
__device__ __forceinline__ int dot8(uint a, uint b, int c) {
#if __has_builtin(__builtin_amdgcn_sdot8)
    return __builtin_amdgcn_sdot8((int)a, (int)b, c, false);
#else
#pragma unroll
    for (int j = 0; j < 8; ++j) c += nib(a, j) * nib(b, j);
    return c;
#endif
}

// Combined prep: blocks [0,256) transpose+quantize z2 -> int4 columns;
// blocks [256,320) do n1map + u8 img table + zero partial2 + zero counter.
__global__ __launch_bounds__(256) void k_prep(const float* __restrict__ v2,
                                              const float* __restrict__ v1,
                                              const float* __restrict__ img,
                                              uchar* __restrict__ z2i4,
                                              float* __restrict__ n1map,
                                              uint* __restrict__ img_u8,
                                              float* __restrict__ partial2,
                                              uint* __restrict__ cnt) {
    int t = threadIdx.x;
    if (blockIdx.x == 0 && t == 0) *cnt = 0u;
    if (blockIdx.x < 256) {
        __shared__ float tile[64][65];
        __shared__ float npart[4][64];
        __shared__ float ninv[64];
        int b  = blockIdx.x >> 6;
        int q0 = (blockIdx.x & 63) * 64;
        int qq = t & 63;
        int cg = t >> 6;
        const float* src = v2 + (size_t)b * C * HW;
        float acc = 0.f;
#pragma unroll
        for (int r = 0; r < 16; ++r) {
            int c = cg * 16 + r;
            float v = src[(size_t)c * HW + q0 + qq];
            tile[c][qq] = v;
            acc += v * v;
        }
        npart[cg][qq] = acc;
        __syncthreads();
        if (t < 64) {
            float s = npart[0][t] + npart[1][t] + npart[2][t] + npart[3][t];
            ninv[t] = QS / fmaxf(sqrtf(s), 1e-8f);
        }
        __syncthreads();
        int qw = t >> 2;
        int c0 = (t & 3) * 16;
        float inv = ninv[qw];
        uint u0 = 0, u1 = 0;
#pragma unroll
        for (int j = 0; j < 8; ++j) {
            int x0 = (int)rintf(tile[c0 + j][qw] * inv);
            int x1 = (int)rintf(tile[c0 + 8 + j][qw] * inv);
            u0 |= (uint)(x0 & 0xF) << (4 * j);
            u1 |= (uint)(x1 & 0xF) << (4 * j);
        }
        uint2* dst = (uint2*)(z2i4 + ((size_t)(b * HW + q0 + qw)) * 32 + (t & 3) * 8);
        *dst = make_uint2(u0, u1);
    } else {
        int bid = blockIdx.x - 256;          // 0..63
        int b = bid >> 4;
        int q = (bid & 15) * 256 + t;
        partial2[bid * 256 + t] = 0.f;       // 64*256 == B*NGRP*NEG
        const float* src = v1 + (size_t)b * C * HW + q;
        float acc = 0.f;
#pragma unroll 8
        for (int c = 0; c < C; ++c) {
            float v = src[(size_t)c * HW];
            acc += v * v;
        }
        n1map[b * HW + q] = sqrtf(acc);
        if (b == 0) {
            uint r  = (uint)rintf(img[q] * 255.f);
            uint g  = (uint)rintf(img[HW + q] * 255.f);
            uint bl = (uint)rintf(img[2 * HW + q] * 255.f);
            img_u8[q] = r | (g << 8) | (bl << 16);
        }
    }
}

// Main: block = (b, 8 pixels). Phase A: {q, f16 w*INVQS2} into LDS (t=k), img from LDS.
// Phase B: ONE lane per column (k=t), 2x dwordx4 int4 loads, v_dot8_i32_i4.
// Tail: last block to finish performs the final reduction and writes out[3].
__global__ __launch_bounds__(256) void k_main(const float* __restrict__ v1,
                                              const int* __restrict__ negh,
                                              const int* __restrict__ negw,
                                              const uchar* __restrict__ z2i4,
                                              const float* __restrict__ n1map,
                                              const uint* __restrict__ img_u8,
                                              float* __restrict__ partial2,
                                              uint* __restrict__ cnt,
                                              float* __restrict__ out) {
    __shared__ __align__(16) uint z1q[CHUNK_P][8];     // int4-packed z1 columns (32B each)
    __shared__ uint qw_lds[CHUNK_P][NEG];              // lo16 = q, hi16 = f16 (w*INVQS2)
    __shared__ uint imgu[HW];                          // 16 KB packed u8 RGB
    int b     = blockIdx.x >> 9;       // NCHUNK = 512
    int chunk = blockIdx.x & 511;
    int p0    = chunk * CHUNK_P;
    int t     = threadIdx.x;

    {   // preload whole img table, coalesced
        uint4* d4 = (uint4*)imgu;
        const uint4* s4 = (const uint4*)img_u8;
#pragma unroll
        for (int j = 0; j < 4; ++j) d4[j * 256 + t] = s4[j * 256 + t];
    }
    if (t < 64) {   // stage z1 columns, normalized xQS -> int4 packed
        int pp = t >> 3;
        int ui = t & 7;                // uint index: channels 8ui..8ui+7
        const float* srcb = v1 + (size_t)b * C * HW + p0 + pp;
        float inv = QS / fmaxf(n1map[b * HW + p0 + pp], 1e-8f);
        uint u = 0;
#pragma unroll
        for (int j = 0; j < 8; ++j) {
            int x = (int)rintf(srcb[(size_t)(8 * ui + j) * HW] * inv);
            u |= (uint)(x & 0xF) << (4 * j);
        }
        z1q[pp][ui] = u;
    }
    __syncthreads();

    const float inv_max_euc = 1.0f / sqrtf((float)((H - 1) * (H - 1) + (W - 1) * (W - 1)));
    const int* nh = negh + ((size_t)b * HW + p0) * NEG + t;
    const int* nw = negw + ((size_t)b * HW + p0) * NEG + t;

    // Phase A: thread t = k index; img lookups from LDS.
#pragma unroll
    for (int pp = 0; pp < CHUNK_P; ++pp) {
        int p = p0 + pp;
        int ih = nh[pp * NEG];
        int iw = nw[pp * NEG];
        int qv = (ih << 6) + iw;
        float dh = (float)(p >> 6) - (float)ih;
        float dw = (float)(p & 63) - (float)iw;
        float euc = sqrtf(dh * dh + dw * dw) * inv_max_euc;
        uint up = imgu[p];
        uint uq = imgu[qv];
        int dr = (int)(up & 255u)         - (int)(uq & 255u);
        int dg = (int)((up >> 8) & 255u)  - (int)((uq >> 8) & 255u);
        int db = (int)((up >> 16) & 255u) - (int)((uq >> 16) & 255u);
        float rgb = sqrtf((float)(dr * dr + dg * dg + db * db)) * RGBNORM;
        float wv = (0.8f * euc + 0.2f * rgb) * INVQS2;
        ushort hb = __builtin_bit_cast(ushort, (_Float16)wv);
        qw_lds[pp][t] = (uint)qv | ((uint)hb << 16);
    }
    __syncthreads();

    // Phase B: lane-per-column; hoisted qw reads; 2 scattered dwordx4 per pixel.
    const uchar* z2b = z2i4 + (size_t)b * HW * 32;
    uint e[CHUNK_P];
#pragma unroll
    for (int pp = 0; pp < CHUNK_P; ++pp) e[pp] = qw_lds[pp][t];
    float acc = 0.f;
#pragma unroll 2
    for (int pp = 0; pp < CHUNK_P; ++pp) {
        uint qv = e[pp] & 0xffffu;
        float wv = (float)__builtin_bit_cast(_Float16, (ushort)(e[pp] >> 16));
        const uint4* cp = (const uint4*)(z2b + (size_t)qv * 32);
        uint4 A0 = cp[0];
        uint4 A1 = cp[1];
        const uint4* zc = (const uint4*)(&z1q[pp][0]);   // uniform -> LDS broadcast
        uint4 u0 = zc[0];
        uint4 u1 = zc[1];
        int di = 0;
        di = dot8(A0.x, u0.x, di);
        di = dot8(A0.y, u0.y, di);
        di = dot8(A0.z, u0.z, di);
        di = dot8(A0.w, u0.w, di);
        di = dot8(A1.x, u1.x, di);
        di = dot8(A1.y, u1.y, di);
        di = dot8(A1.z, u1.z, di);
        di = dot8(A1.w, u1.w, di);
        acc += fminf(fabsf((float)di * wv), 1.0f);
    }
    atomicAdd(&partial2[((size_t)b * NGRP + (chunk >> 5)) * NEG + t], acc);

    // ---- completion: last block performs the final reduction ----
    __threadfence();
    __shared__ int isLast;
    if (t == 0) {
        uint prev = atomicAdd(cnt, 1u);
        isLast = (prev == (uint)(NBLK - 1));
    }
    __syncthreads();
    if (!isLast) return;
    __threadfence();

    __shared__ float xw[3][4];
    int lane = t & 63;
    int wid  = t >> 6;
    float bsum = 0.f, s0sum = 0.f, snegsum = 0.f;
    for (int bb = 0; bb < B; ++bb) {
        float s = 0.f;
#pragma unroll
        for (int g = 0; g < NGRP; ++g)
            s += __hip_atomic_load(&partial2[((size_t)bb * NGRP + g) * NEG + t],
                                   __ATOMIC_RELAXED, __HIP_MEMORY_SCOPE_AGENT);
        float sneg = s * (1.0f / HW) * 0.5f;               // / HW / TEMPERATURE
        float l1m  = fmaxf(logf(1.0f - sneg), -100.0f);
        float ss = 0.f;
#pragma unroll
        for (int j = 0; j < HW / 256; ++j) {
            float n1 = n1map[bb * HW + j * 256 + t];
            float n1sq = n1 * n1;
            ss += fminf(n1sq / fmaxf(n1sq, 1e-8f), 1.0f);
        }
        float r0 = sneg, r1 = l1m, r2 = ss;
#pragma unroll
        for (int o = 1; o < 64; o <<= 1) {
            r0 += __shfl_xor(r0, o);
            r1 += __shfl_xor(r1, o);
            r2 += __shfl_xor(r2, o);
        }
        if (lane == 0) { xw[0][wid] = r0; xw[1][wid] = r1; xw[2][wid] = r2; }
        __syncthreads();
        if (t == 0) {
            float sn = xw[0][0] + xw[0][1] + xw[0][2] + xw[0][3];
            float lm = xw[1][0] + xw[1][1] + xw[1][2] + xw[1][3];
            float sv = xw[2][0] + xw[2][1] + xw[2][2] + xw[2][3];
            float s0 = sv * (1.0f / HW);
            bsum    += -(fmaxf(logf(s0), -100.0f) + lm) * (1.0f / (NEG + 1));
            s0sum   += s0;
            snegsum += sn;
        }
        __syncthreads();
    }
    if (t == 0) {
        out[0] = bsum * 0.25f;                              // mean bce
        out[1] = s0sum * 0.25f;                             // sim_all[0] / B
        out[2] = snegsum * (1.0f / NEG) * 2.0f * 0.25f;     // sum/NEG*TEMP/B
    }
}

extern "C" void kernel_launch(void* const* d_in, const int* in_sizes, int n_in,
                              void* d_out, int out_size, void* d_ws, size_t ws_size,
                              hipStream_t stream) {
    const float* v1   = (const float*)d_in[0];
    const float* v2   = (const float*)d_in[1];
    const float* img  = (const float*)d_in[2];
    const int*   negh = (const int*)d_in[3];
    const int*   negw = (const int*)d_in[4];
    float* out = (float*)d_out;
    float* ws  = (float*)d_ws;

    uchar* z2i4     = (uchar*)(ws + OFF_Z2T);
    float* n1map    = ws + OFF_N1MAP;
    uint*  img_u8   = (uint*)(ws + OFF_IMGU8);
    float* partial2 = ws + OFF_PART2;
    uint*  cnt      = (uint*)(ws + OFF_CNT);

    hipLaunchKernelGGL(k_prep, dim3(320), dim3(256), 0, stream,
                       v2, v1, img, z2i4, n1map, img_u8, partial2, cnt);
    hipLaunchKernelGGL(k_main, dim3(NBLK), dim3(256), 0, stream,
                       v1, negh, negw, z2i4, n1map, img_u8, partial2, cnt, out);
}

// Round 11
// 43.189 us; speedup vs baseline: 4.6266x; 4.6266x over previous
//
#include <hip/hip_runtime.h>
#include <math.h>

typedef unsigned short ushort;
typedef unsigned int uint;
typedef unsigned char uchar;

#define B 4
#define C 64
#define H 64
#define W 64
#define HW 4096
#define NEG 256
#define CHUNK_P 8
#define NCHUNK (HW / CHUNK_P)   // 512
#define NGRP 16

#define QS 7.49f
#define INVQS2 (1.0f / (QS * QS))
#define RGBNORM5 0.0186243f      // 1/(31*sqrt(3))

// ---------------- ws layout (float units) ----------------
// z2i4   : [B][HW][32B] int4 (column pre-normalized, xQS) = B*HW*8 floats
// n1map  : [B][HW]
// imgu16 : [HW] ushort (packed RGB555) = HW/2 floats
// partial2:[B][NGRP][NEG]  (atomically accumulated; zeroed by k_prep)
#define OFF_Z2T     0
#define OFF_N1MAP   (OFF_Z2T + B*HW*8)
#define OFF_IMGU16  (OFF_N1MAP + B*HW)
#define OFF_PART2   (OFF_IMGU16 + HW/2)

__device__ __forceinline__ int nib(uint u, int j) {
    return ((int)(u << (28 - 4 * j))) >> 28;
}
__device__ __forceinline__ int dot8(uint a, uint b, int c) {
#if __has_builtin(__builtin_amdgcn_sdot8)
    return __builtin_amdgcn_sdot8((int)a, (int)b, c, false);
#else
#pragma unroll
    for (int j = 0; j < 8; ++j) c += nib(a, j) * nib(b, j);
    return c;
#endif
}

// Combined prep: blocks [0,256) transpose+quantize z2 -> int4 columns;
// blocks [256,320) do n1map + RGB555 img table + zero partial2.
__global__ __launch_bounds__(256) void k_prep(const float* __restrict__ v2,
                                              const float* __restrict__ v1,
                                              const float* __restrict__ img,
                                              uchar* __restrict__ z2i4,
                                              float* __restrict__ n1map,
                                              ushort* __restrict__ img_u16,
                                              float* __restrict__ partial2) {
    int t = threadIdx.x;
    if (blockIdx.x < 256) {
        __shared__ float tile[64][65];
        __shared__ float npart[4][64];
        __shared__ float ninv[64];
        int b  = blockIdx.x >> 6;
        int q0 = (blockIdx.x & 63) * 64;
        int qq = t & 63;
        int cg = t >> 6;
        const float* src = v2 + (size_t)b * C * HW;
        float acc = 0.f;
#pragma unroll
        for (int r = 0; r < 16; ++r) {
            int c = cg * 16 + r;
            float v = src[(size_t)c * HW + q0 + qq];
            tile[c][qq] = v;
            acc += v * v;
        }
        npart[cg][qq] = acc;
        __syncthreads();
        if (t < 64) {
            float s = npart[0][t] + npart[1][t] + npart[2][t] + npart[3][t];
            ninv[t] = QS / fmaxf(sqrtf(s), 1e-8f);
        }
        __syncthreads();
        int qw = t >> 2;
        int c0 = (t & 3) * 16;
        float inv = ninv[qw];
        uint u0 = 0, u1 = 0;
#pragma unroll
        for (int j = 0; j < 8; ++j) {
            int x0 = (int)rintf(tile[c0 + j][qw] * inv);
            int x1 = (int)rintf(tile[c0 + 8 + j][qw] * inv);
            u0 |= (uint)(x0 & 0xF) << (4 * j);
            u1 |= (uint)(x1 & 0xF) << (4 * j);
        }
        uint2* dst = (uint2*)(z2i4 + ((size_t)(b * HW + q0 + qw)) * 32 + (t & 3) * 8);
        *dst = make_uint2(u0, u1);
    } else {
        int bid = blockIdx.x - 256;          // 0..63
        int b = bid >> 4;
        int q = (bid & 15) * 256 + t;
        partial2[bid * 256 + t] = 0.f;       // 64*256 == B*NGRP*NEG
        const float* src = v1 + (size_t)b * C * HW + q;
        float acc = 0.f;
#pragma unroll 8
        for (int c = 0; c < C; ++c) {
            float v = src[(size_t)c * HW];
            acc += v * v;
        }
        n1map[b * HW + q] = sqrtf(acc);
        if (b == 0) {
            uint r  = (uint)rintf(img[q] * 31.f);
            uint g  = (uint)rintf(img[HW + q] * 31.f);
            uint bl = (uint)rintf(img[2 * HW + q] * 31.f);
            img_u16[q] = (ushort)(r | (g << 5) | (bl << 10));
        }
    }
}

// Main: block = (b, 8 pixels). Phase A: {q, f16 w*INVQS2} into LDS (t=k), img from LDS.
// Phase B: ONE lane per column (k=t), 2x dwordx4 int4 loads, v_dot8_i32_i4.
// LDS ~16.3 KB -> 8 blocks/CU (full wave occupancy).
__global__ __launch_bounds__(256) void k_main(const float* __restrict__ v1,
                                              const int* __restrict__ negh,
                                              const int* __restrict__ negw,
                                              const uchar* __restrict__ z2i4,
                                              const float* __restrict__ n1map,
                                              const ushort* __restrict__ img_u16,
                                              float* __restrict__ partial2) {
    __shared__ __align__(16) uint z1q[CHUNK_P][8];     // int4-packed z1 columns (32B each)
    __shared__ uint qw_lds[CHUNK_P][NEG];              // lo16 = q, hi16 = f16 (w*INVQS2)
    __shared__ ushort imgu[HW];                        // 8 KB packed RGB555
    int b     = blockIdx.x >> 9;       // NCHUNK = 512
    int chunk = blockIdx.x & 511;
    int p0    = chunk * CHUNK_P;
    int t     = threadIdx.x;

    {   // preload whole img table, coalesced (8 KB = 512 uint4)
        uint4* d4 = (uint4*)imgu;
        const uint4* s4 = (const uint4*)img_u16;
        d4[t]       = s4[t];
        d4[256 + t] = s4[256 + t];
    }
    if (t < 64) {   // stage z1 columns, normalized xQS -> int4 packed
        int pp = t >> 3;
        int ui = t & 7;                // uint index: channels 8ui..8ui+7
        const float* srcb = v1 + (size_t)b * C * HW + p0 + pp;
        float inv = QS / fmaxf(n1map[b * HW + p0 + pp], 1e-8f);
        uint u = 0;
#pragma unroll
        for (int j = 0; j < 8; ++j) {
            int x = (int)rintf(srcb[(size_t)(8 * ui + j) * HW] * inv);
            u |= (uint)(x & 0xF) << (4 * j);
        }
        z1q[pp][ui] = u;
    }
    __syncthreads();

    const float inv_max_euc = 1.0f / sqrtf((float)((H - 1) * (H - 1) + (W - 1) * (W - 1)));
    const int* nh = negh + ((size_t)b * HW + p0) * NEG + t;
    const int* nw = negw + ((size_t)b * HW + p0) * NEG + t;

    // Phase A: thread t = k index; img lookups from LDS.
#pragma unroll
    for (int pp = 0; pp < CHUNK_P; ++pp) {
        int p = p0 + pp;
        int ih = nh[pp * NEG];
        int iw = nw[pp * NEG];
        int qv = (ih << 6) + iw;
        float dh = (float)(p >> 6) - (float)ih;
        float dw = (float)(p & 63) - (float)iw;
        float euc = sqrtf(dh * dh + dw * dw) * inv_max_euc;
        uint up = imgu[p];
        uint uq = imgu[qv];
        int dr = (int)(up & 31u)         - (int)(uq & 31u);
        int dg = (int)((up >> 5) & 31u)  - (int)((uq >> 5) & 31u);
        int db = (int)((up >> 10) & 31u) - (int)((uq >> 10) & 31u);
        float rgb = sqrtf((float)(dr * dr + dg * dg + db * db)) * RGBNORM5;
        float wv = (0.8f * euc + 0.2f * rgb) * INVQS2;
        ushort hb = __builtin_bit_cast(ushort, (_Float16)wv);
        qw_lds[pp][t] = (uint)qv | ((uint)hb << 16);
    }
    __syncthreads();

    // Phase B: lane-per-column; hoisted qw reads; 2 scattered dwordx4 per pixel.
    const uchar* z2b = z2i4 + (size_t)b * HW * 32;
    uint e[CHUNK_P];
#pragma unroll
    for (int pp = 0; pp < CHUNK_P; ++pp) e[pp] = qw_lds[pp][t];
    float acc = 0.f;
#pragma unroll 2
    for (int pp = 0; pp < CHUNK_P; ++pp) {
        uint qv = e[pp] & 0xffffu;
        float wv = (float)__builtin_bit_cast(_Float16, (ushort)(e[pp] >> 16));
        const uint4* cp = (const uint4*)(z2b + (size_t)qv * 32);
        uint4 A0 = cp[0];
        uint4 A1 = cp[1];
        const uint4* zc = (const uint4*)(&z1q[pp][0]);   // uniform -> LDS broadcast
        uint4 u0 = zc[0];
        uint4 u1 = zc[1];
        int di = 0;
        di = dot8(A0.x, u0.x, di);
        di = dot8(A0.y, u0.y, di);
        di = dot8(A0.z, u0.z, di);
        di = dot8(A0.w, u0.w, di);
        di = dot8(A1.x, u1.x, di);
        di = dot8(A1.y, u1.y, di);
        di = dot8(A1.z, u1.z, di);
        di = dot8(A1.w, u1.w, di);
        acc += fminf(fabsf((float)di * wv), 1.0f);
    }
    atomicAdd(&partial2[((size_t)b * NGRP + (chunk >> 5)) * NEG + t], acc);
}

// Merged stage-2 + final with shfl wave reductions.
__global__ __launch_bounds__(256) void k_reduce2f(const float* __restrict__ partial2,
                                                  const float* __restrict__ n1map,
                                                  float* __restrict__ out) {
    __shared__ float xw[3][4];
    int t = threadIdx.x;
    int lane = t & 63;
    int wid  = t >> 6;
    float bsum = 0.f, s0sum = 0.f, snegsum = 0.f;
    for (int b = 0; b < B; ++b) {
        float s = 0.f;
#pragma unroll
        for (int g = 0; g < NGRP; ++g)
            s += partial2[((size_t)b * NGRP + g) * NEG + t];
        float sneg = s * (1.0f / HW) * 0.5f;               // / HW / TEMPERATURE
        float l1m  = fmaxf(logf(1.0f - sneg), -100.0f);
        float ss = 0.f;
#pragma unroll
        for (int j = 0; j < HW / 256; ++j) {
            float n1 = n1map[b * HW + j * 256 + t];
            float n1sq = n1 * n1;
            ss += fminf(n1sq / fmaxf(n1sq, 1e-8f), 1.0f);
        }
        float r0 = sneg, r1 = l1m, r2 = ss;
#pragma unroll
        for (int o = 1; o < 64; o <<= 1) {
            r0 += __shfl_xor(r0, o);
            r1 += __shfl_xor(r1, o);
            r2 += __shfl_xor(r2, o);
        }
        if (lane == 0) { xw[0][wid] = r0; xw[1][wid] = r1; xw[2][wid] = r2; }
        __syncthreads();
        if (t == 0) {
            float sn = xw[0][0] + xw[0][1] + xw[0][2] + xw[0][3];
            float lm = xw[1][0] + xw[1][1] + xw[1][2] + xw[1][3];
            float sv = xw[2][0] + xw[2][1] + xw[2][2] + xw[2][3];
            float s0 = sv * (1.0f / HW);
            bsum    += -(fmaxf(logf(s0), -100.0f) + lm) * (1.0f / (NEG + 1));
            s0sum   += s0;
            snegsum += sn;
        }
        __syncthreads();
    }
    if (t == 0) {
        out[0] = bsum * 0.25f;                              // mean bce
        out[1] = s0sum * 0.25f;                             // sim_all[0] / B
        out[2] = snegsum * (1.0f / NEG) * 2.0f * 0.25f;     // sum/NEG*TEMP/B
    }
}

extern "C" void kernel_launch(void* const* d_in, const int* in_sizes, int n_in,
                              void* d_out, int out_size, void* d_ws, size_t ws_size,
                              hipStream_t stream) {
    const float* v1   = (const float*)d_in[0];
    const float* v2   = (const float*)d_in[1];
    const float* img  = (const float*)d_in[2];
    const int*   negh = (const int*)d_in[3];
    const int*   negw = (const int*)d_in[4];
    float* out = (float*)d_out;
    float* ws  = (float*)d_ws;

    uchar*  z2i4     = (uchar*)(ws + OFF_Z2T);
    float*  n1map    = ws + OFF_N1MAP;
    ushort* img_u16  = (ushort*)(ws + OFF_IMGU16);
    float*  partial2 = ws + OFF_PART2;

    hipLaunchKernelGGL(k_prep, dim3(320), dim3(256), 0, stream,
                       v2, v1, img, z2i4, n1map, img_u16, partial2);
    hipLaunchKernelGGL(k_main, dim3(B * NCHUNK), dim3(256), 0, stream,
                       v1, negh, negw, z2i4, n1map, img_u16, partial2);
    hipLaunchKernelGGL(k_reduce2f, dim3(1), dim3(256), 0, stream, partial2, n1map, out);
}

// Round 12
// 42.901 us; speedup vs baseline: 4.6577x; 1.0067x over previous
//
#include <hip/hip_runtime.h>
#include <math.h>

typedef unsigned short ushort;
typedef unsigned int uint;
typedef unsigned char uchar;

#define B 4
#define C 64
#define H 64
#define W 64
#define HW 4096
#define NEG 256
#define CHUNK_P 8
#define NCHUNK (HW / CHUNK_P)   // 512
#define NGRP 16

#define QS 7.49f
#define INVQS2 (1.0f / (QS * QS))
#define RGBNORM5 0.0186243f      // 1/(31*sqrt(3))

// ---------------- ws layout (float units) ----------------
// z2i4   : [B][HW][32B] int4 (column pre-normalized, xQS) = B*HW*8 floats
// n1map  : [B][HW]
// imgu16 : [HW] ushort (packed RGB555) = HW/2 floats
// partial2:[B][NGRP][NEG]  (atomically accumulated; zeroed by k_prep)
#define OFF_Z2T     0
#define OFF_N1MAP   (OFF_Z2T + B*HW*8)
#define OFF_IMGU16  (OFF_N1MAP + B*HW)
#define OFF_PART2   (OFF_IMGU16 + HW/2)

__device__ __forceinline__ int nib(uint u, int j) {
    return ((int)(u << (28 - 4 * j))) >> 28;
}
__device__ __forceinline__ int dot8(uint a, uint b, int c) {
#if __has_builtin(__builtin_amdgcn_sdot8)
    return __builtin_amdgcn_sdot8((int)a, (int)b, c, false);
#else
#pragma unroll
    for (int j = 0; j < 8; ++j) c += nib(a, j) * nib(b, j);
    return c;
#endif
}

// Combined prep: blocks [0,256) transpose+quantize z2 -> int4 columns;
// blocks [256,320) do n1map + RGB555 img table + zero partial2.
__global__ __launch_bounds__(256) void k_prep(const float* __restrict__ v2,
                                              const float* __restrict__ v1,
                                              const float* __restrict__ img,
                                              uchar* __restrict__ z2i4,
                                              float* __restrict__ n1map,
                                              ushort* __restrict__ img_u16,
                                              float* __restrict__ partial2) {
    int t = threadIdx.x;
    if (blockIdx.x < 256) {
        __shared__ float tile[64][65];
        __shared__ float npart[4][64];
        __shared__ float ninv[64];
        int b  = blockIdx.x >> 6;
        int q0 = (blockIdx.x & 63) * 64;
        int qq = t & 63;
        int cg = t >> 6;
        const float* src = v2 + (size_t)b * C * HW;
        float acc = 0.f;
#pragma unroll
        for (int r = 0; r < 16; ++r) {
            int c = cg * 16 + r;
            float v = src[(size_t)c * HW + q0 + qq];
            tile[c][qq] = v;
            acc += v * v;
        }
        npart[cg][qq] = acc;
        __syncthreads();
        if (t < 64) {
            float s = npart[0][t] + npart[1][t] + npart[2][t] + npart[3][t];
            ninv[t] = QS / fmaxf(sqrtf(s), 1e-8f);
        }
        __syncthreads();
        int qw = t >> 2;
        int c0 = (t & 3) * 16;
        float inv = ninv[qw];
        uint u0 = 0, u1 = 0;
#pragma unroll
        for (int j = 0; j < 8; ++j) {
            int x0 = (int)rintf(tile[c0 + j][qw] * inv);
            int x1 = (int)rintf(tile[c0 + 8 + j][qw] * inv);
            u0 |= (uint)(x0 & 0xF) << (4 * j);
            u1 |= (uint)(x1 & 0xF) << (4 * j);
        }
        uint2* dst = (uint2*)(z2i4 + ((size_t)(b * HW + q0 + qw)) * 32 + (t & 3) * 8);
        *dst = make_uint2(u0, u1);
    } else {
        int bid = blockIdx.x - 256;          // 0..63
        int b = bid >> 4;
        int q = (bid & 15) * 256 + t;
        partial2[bid * 256 + t] = 0.f;       // 64*256 == B*NGRP*NEG
        const float* src = v1 + (size_t)b * C * HW + q;
        float acc = 0.f;
#pragma unroll 8
        for (int c = 0; c < C; ++c) {
            float v = src[(size_t)c * HW];
            acc += v * v;
        }
        n1map[b * HW + q] = sqrtf(acc);
        if (b == 0) {
            uint r  = (uint)rintf(img[q] * 31.f);
            uint g  = (uint)rintf(img[HW + q] * 31.f);
            uint bl = (uint)rintf(img[2 * HW + q] * 31.f);
            img_u16[q] = (ushort)(r | (g << 5) | (bl << 10));
        }
    }
}

// Main: block = (b, 8 pixels); thread t = k index for every pixel.
// FUSED: per pixel, idx load -> weight (img from LDS) -> scattered int4 column
// gather -> v_dot8_i32_i4, all in registers; 8 independent chains unrolled.
__global__ __launch_bounds__(256) void k_main(const float* __restrict__ v1,
                                              const int* __restrict__ negh,
                                              const int* __restrict__ negw,
                                              const uchar* __restrict__ z2i4,
                                              const float* __restrict__ n1map,
                                              const ushort* __restrict__ img_u16,
                                              float* __restrict__ partial2) {
    __shared__ __align__(16) uint z1q[CHUNK_P][8];     // int4-packed z1 columns (32B each)
    __shared__ ushort imgu[HW];                        // 8 KB packed RGB555
    int b     = blockIdx.x >> 9;       // NCHUNK = 512
    int chunk = blockIdx.x & 511;
    int p0    = chunk * CHUNK_P;
    int t     = threadIdx.x;

    {   // preload whole img table, coalesced (8 KB = 512 uint4)
        uint4* d4 = (uint4*)imgu;
        const uint4* s4 = (const uint4*)img_u16;
        d4[t]       = s4[t];
        d4[256 + t] = s4[256 + t];
    }
    if (t < 64) {   // stage z1 columns, normalized xQS -> int4 packed
        int pp = t >> 3;
        int ui = t & 7;                // uint index: channels 8ui..8ui+7
        const float* srcb = v1 + (size_t)b * C * HW + p0 + pp;
        float inv = QS / fmaxf(n1map[b * HW + p0 + pp], 1e-8f);
        uint u = 0;
#pragma unroll
        for (int j = 0; j < 8; ++j) {
            int x = (int)rintf(srcb[(size_t)(8 * ui + j) * HW] * inv);
            u |= (uint)(x & 0xF) << (4 * j);
        }
        z1q[pp][ui] = u;
    }
    __syncthreads();

    const float inv_max_euc = 1.0f / sqrtf((float)((H - 1) * (H - 1) + (W - 1) * (W - 1)));
    const int* nh = negh + ((size_t)b * HW + p0) * NEG + t;
    const int* nw = negw + ((size_t)b * HW + p0) * NEG + t;
    const uchar* z2b = z2i4 + (size_t)b * HW * 32;

    float acc = 0.f;
#pragma unroll
    for (int pp = 0; pp < CHUNK_P; ++pp) {
        int p = p0 + pp;
        int ih = nh[pp * NEG];
        int iw = nw[pp * NEG];
        int qv = (ih << 6) + iw;
        // weight in registers
        float dh = (float)(p >> 6) - (float)ih;
        float dw = (float)(p & 63) - (float)iw;
        float euc = sqrtf(dh * dh + dw * dw) * inv_max_euc;
        uint up = imgu[p];                 // wave-uniform -> LDS broadcast
        uint uq = imgu[qv];
        int dr = (int)(up & 31u)         - (int)(uq & 31u);
        int dg = (int)((up >> 5) & 31u)  - (int)((uq >> 5) & 31u);
        int db = (int)((up >> 10) & 31u) - (int)((uq >> 10) & 31u);
        float rgb = sqrtf((float)(dr * dr + dg * dg + db * db)) * RGBNORM5;
        float wv = (0.8f * euc + 0.2f * rgb) * INVQS2;
        // scattered column gather + int4 dot
        const uint4* cp = (const uint4*)(z2b + (size_t)qv * 32);
        uint4 A0 = cp[0];
        uint4 A1 = cp[1];
        const uint4* zc = (const uint4*)(&z1q[pp][0]);   // uniform -> LDS broadcast
        uint4 u0 = zc[0];
        uint4 u1 = zc[1];
        int di = 0;
        di = dot8(A0.x, u0.x, di);
        di = dot8(A0.y, u0.y, di);
        di = dot8(A0.z, u0.z, di);
        di = dot8(A0.w, u0.w, di);
        di = dot8(A1.x, u1.x, di);
        di = dot8(A1.y, u1.y, di);
        di = dot8(A1.z, u1.z, di);
        di = dot8(A1.w, u1.w, di);
        acc += fminf(fabsf((float)di * wv), 1.0f);
    }
    atomicAdd(&partial2[((size_t)b * NGRP + (chunk >> 5)) * NEG + t], acc);
}

// Merged stage-2 + final with shfl wave reductions.
__global__ __launch_bounds__(256) void k_reduce2f(const float* __restrict__ partial2,
                                                  const float* __restrict__ n1map,
                                                  float* __restrict__ out) {
    __shared__ float xw[3][4];
    int t = threadIdx.x;
    int lane = t & 63;
    int wid  = t >> 6;
    float bsum = 0.f, s0sum = 0.f, snegsum = 0.f;
    for (int b = 0; b < B; ++b) {
        float s = 0.f;
#pragma unroll
        for (int g = 0; g < NGRP; ++g)
            s += partial2[((size_t)b * NGRP + g) * NEG + t];
        float sneg = s * (1.0f / HW) * 0.5f;               // / HW / TEMPERATURE
        float l1m  = fmaxf(logf(1.0f - sneg), -100.0f);
        float ss = 0.f;
#pragma unroll
        for (int j = 0; j < HW / 256; ++j) {
            float n1 = n1map[b * HW + j * 256 + t];
            float n1sq = n1 * n1;
            ss += fminf(n1sq / fmaxf(n1sq, 1e-8f), 1.0f);
        }
        float r0 = sneg, r1 = l1m, r2 = ss;
#pragma unroll
        for (int o = 1; o < 64; o <<= 1) {
            r0 += __shfl_xor(r0, o);
            r1 += __shfl_xor(r1, o);
            r2 += __shfl_xor(r2, o);
        }
        if (lane == 0) { xw[0][wid] = r0; xw[1][wid] = r1; xw[2][wid] = r2; }
        __syncthreads();
        if (t == 0) {
            float sn = xw[0][0] + xw[0][1] + xw[0][2] + xw[0][3];
            float lm = xw[1][0] + xw[1][1] + xw[1][2] + xw[1][3];
            float sv = xw[2][0] + xw[2][1] + xw[2][2] + xw[2][3];
            float s0 = sv * (1.0f / HW);
            bsum    += -(fmaxf(logf(s0), -100.0f) + lm) * (1.0f / (NEG + 1));
            s0sum   += s0;
            snegsum += sn;
        }
        __syncthreads();
    }
    if (t == 0) {
        out[0] = bsum * 0.25f;                              // mean bce
        out[1] = s0sum * 0.25f;                             // sim_all[0] / B
        out[2] = snegsum * (1.0f / NEG) * 2.0f * 0.25f;     // sum/NEG*TEMP/B
    }
}

extern "C" void kernel_launch(void* const* d_in, const int* in_sizes, int n_in,
                              void* d_out, int out_size, void* d_ws, size_t ws_size,
                              hipStream_t stream) {
    const float* v1   = (const float*)d_in[0];
    const float* v2   = (const float*)d_in[1];
    const float* img  = (const float*)d_in[2];
    const int*   negh = (const int*)d_in[3];
    const int*   negw = (const int*)d_in[4];
    float* out = (float*)d_out;
    float* ws  = (float*)d_ws;

    uchar*  z2i4     = (uchar*)(ws + OFF_Z2T);
    float*  n1map    = ws + OFF_N1MAP;
    ushort* img_u16  = (ushort*)(ws + OFF_IMGU16);
    float*  partial2 = ws + OFF_PART2;

    hipLaunchKernelGGL(k_prep, dim3(320), dim3(256), 0, stream,
                       v2, v1, img, z2i4, n1map, img_u16, partial2);
    hipLaunchKernelGGL(k_main, dim3(B * NCHUNK), dim3(256), 0, stream,
                       v1, negh, negw, z2i4, n1map, img_u16, partial2);
    hipLaunchKernelGGL(k_reduce2f, dim3(1), dim3(256), 0, stream, partial2, n1map, out);
}

// Round 13
// 36.758 us; speedup vs baseline: 5.4361x; 1.1671x over previous
//
#include <hip/hip_runtime.h>
#include <math.h>

typedef unsigned short ushort;
typedef unsigned int uint;
typedef unsigned char uchar;

#define B 4
#define C 64
#define H 64
#define W 64
#define HW 4096
#define NEG 256
#define NGRP 16
#define PXB 64                   // pixels per k_main block
#define NBLK (B * HW / PXB)      // 256 blocks = 1 per CU

#define QS 7.49f
#define INVQS2 (1.0f / (QS * QS))
#define RGBNORM5 0.0186243f      // 1/(31*sqrt(3))

// ---------------- ws layout (float units) ----------------
// z2A    : [B][HW] uint4 (channels 0-31,  int4 packed)  = B*HW*4 floats
// z2B    : [B][HW] uint4 (channels 32-63, int4 packed)  = B*HW*4 floats
// n1map  : [B][HW]
// imgu16 : [HW] ushort RGB555 = HW/2 floats
// partial2:[B][NGRP][NEG]  (atomically accumulated; zeroed by k_prep)
#define OFF_Z2A    0
#define OFF_Z2B    (OFF_Z2A + B*HW*4)
#define OFF_N1MAP  (OFF_Z2B + B*HW*4)
#define OFF_IMGU16 (OFF_N1MAP + B*HW)
#define OFF_PART2  (OFF_IMGU16 + HW/2)

__device__ __forceinline__ int nib(uint u, int j) {
    return ((int)(u << (28 - 4 * j))) >> 28;
}
__device__ __forceinline__ int dot8(uint a, uint b, int c) {
#if __has_builtin(__builtin_amdgcn_sdot8)
    return __builtin_amdgcn_sdot8((int)a, (int)b, c, false);
#else
#pragma unroll
    for (int j = 0; j < 8; ++j) c += nib(a, j) * nib(b, j);
    return c;
#endif
}

// Combined prep: blocks [0,256) transpose+quantize z2 -> split int4 columns (A/B);
// blocks [256,320) do n1map + RGB555 img table + zero partial2.
__global__ __launch_bounds__(256) void k_prep(const float* __restrict__ v2,
                                              const float* __restrict__ v1,
                                              const float* __restrict__ img,
                                              uchar* __restrict__ z2Ag,
                                              uchar* __restrict__ z2Bg,
                                              float* __restrict__ n1map,
                                              ushort* __restrict__ img_u16,
                                              float* __restrict__ partial2) {
    int t = threadIdx.x;
    if (blockIdx.x < 256) {
        __shared__ float tile[64][65];
        __shared__ float npart[4][64];
        __shared__ float ninv[64];
        int b  = blockIdx.x >> 6;
        int q0 = (blockIdx.x & 63) * 64;
        int qq = t & 63;
        int cg = t >> 6;
        const float* src = v2 + (size_t)b * C * HW;
        float acc = 0.f;
#pragma unroll
        for (int r = 0; r < 16; ++r) {
            int c = cg * 16 + r;
            float v = src[(size_t)c * HW + q0 + qq];
            tile[c][qq] = v;
            acc += v * v;
        }
        npart[cg][qq] = acc;
        __syncthreads();
        if (t < 64) {
            float s = npart[0][t] + npart[1][t] + npart[2][t] + npart[3][t];
            ninv[t] = QS / fmaxf(sqrtf(s), 1e-8f);
        }
        __syncthreads();
        int qw   = t >> 2;
        int quad = t & 3;
        int c0   = quad * 16;
        float inv = ninv[qw];
        uint u0 = 0, u1 = 0;
#pragma unroll
        for (int j = 0; j < 8; ++j) {
            int x0 = (int)rintf(tile[c0 + j][qw] * inv);
            int x1 = (int)rintf(tile[c0 + 8 + j][qw] * inv);
            u0 |= (uint)(x0 & 0xF) << (4 * j);
            u1 |= (uint)(x1 & 0xF) << (4 * j);
        }
        size_t col = (size_t)b * HW + q0 + qw;
        uint2 val = make_uint2(u0, u1);
        if (quad < 2) *(uint2*)(z2Ag + col * 16 + quad * 8)       = val;
        else          *(uint2*)(z2Bg + col * 16 + (quad - 2) * 8) = val;
    } else {
        int bid = blockIdx.x - 256;          // 0..63
        int b = bid >> 4;
        int q = (bid & 15) * 256 + t;
        partial2[bid * 256 + t] = 0.f;       // 64*256 == B*NGRP*NEG
        const float* src = v1 + (size_t)b * C * HW + q;
        float acc = 0.f;
#pragma unroll 8
        for (int c = 0; c < C; ++c) {
            float v = src[(size_t)c * HW];
            acc += v * v;
        }
        n1map[b * HW + q] = sqrtf(acc);
        if (b == 0) {
            uint r  = (uint)rintf(img[q] * 31.f);
            uint g  = (uint)rintf(img[HW + q] * 31.f);
            uint bl = (uint)rintf(img[2 * HW + q] * 31.f);
            img_u16[q] = (ushort)(r | (g << 5) | (bl << 10));
        }
    }
}

// Main: 256 blocks x 512 threads, 1 block/CU. The ENTIRE item z2 (128 KB int4,
// split A/B for aligned b128 reads) + img table live in LDS. Thread = (k, px-half),
// 64 pixels per block; all gathers are LDS reads. ~138 KB LDS.
__global__ __launch_bounds__(512) void k_main(const float* __restrict__ v1,
                                              const int* __restrict__ negh,
                                              const int* __restrict__ negw,
                                              const uint4* __restrict__ z2Ag,
                                              const uint4* __restrict__ z2Bg,
                                              const float* __restrict__ n1map,
                                              const ushort* __restrict__ img_u16,
                                              float* __restrict__ partial2) {
    __shared__ uint4 zA[HW];                // 64 KB: channels 0-31 per column
    __shared__ uint4 zB[HW];                // 64 KB: channels 32-63 per column
    __shared__ ushort imgu[HW];             // 8 KB RGB555
    __shared__ uint z1q[PXB][8];            // 2 KB int4-packed z1 columns
    int b  = blockIdx.x >> 6;
    int p0 = (blockIdx.x & 63) * PXB;
    int t  = threadIdx.x;

    {   // stage whole-item z2 (A/B) + img table, fully coalesced
        const uint4* gA = z2Ag + (size_t)b * HW;
        const uint4* gB = z2Bg + (size_t)b * HW;
#pragma unroll
        for (int i = 0; i < 8; ++i) {
            zA[i * 512 + t] = gA[i * 512 + t];
            zB[i * 512 + t] = gB[i * 512 + t];
        }
        ((uint4*)imgu)[t & 511] = ((const uint4*)img_u16)[t & 511];  // 512 uint4
    }
    {   // stage z1 columns, normalized xQS -> int4 packed (64 px x 8 uints)
        int px = t >> 3;
        int ui = t & 7;
        const float* srcb = v1 + (size_t)b * C * HW + p0 + px;
        float inv = QS / fmaxf(n1map[b * HW + p0 + px], 1e-8f);
        uint u = 0;
#pragma unroll
        for (int j = 0; j < 8; ++j) {
            int x = (int)rintf(srcb[(size_t)(8 * ui + j) * HW] * inv);
            u |= (uint)(x & 0xF) << (4 * j);
        }
        z1q[px][ui] = u;
    }
    __syncthreads();

    const float inv_max_euc = 1.0f / sqrtf((float)((H - 1) * (H - 1) + (W - 1) * (W - 1)));
    int k    = t & 255;
    int half = t >> 8;
    int pbase = p0 + half * 32;
    const int* nh = negh + ((size_t)b * HW + pbase) * NEG + k;
    const int* nw = negw + ((size_t)b * HW + pbase) * NEG + k;

    float acc = 0.f;
#pragma unroll 2
    for (int j0 = 0; j0 < 32; j0 += 8) {
        int ihv[8], iwv[8];
#pragma unroll
        for (int j = 0; j < 8; ++j) {
            ihv[j] = nh[(j0 + j) * NEG];
            iwv[j] = nw[(j0 + j) * NEG];
        }
#pragma unroll
        for (int j = 0; j < 8; ++j) {
            int px = half * 32 + j0 + j;
            int p  = pbase + j0 + j;
            int ih = ihv[j], iw = iwv[j];
            int qv = (ih << 6) + iw;
            // weight
            float dh = (float)(p >> 6) - (float)ih;
            float dw = (float)(p & 63) - (float)iw;
            float euc = sqrtf(dh * dh + dw * dw) * inv_max_euc;
            uint up = imgu[p];                 // wave-uniform -> broadcast
            uint uq = imgu[qv];                // scattered LDS u16
            int dr = (int)(up & 31u)         - (int)(uq & 31u);
            int dg = (int)((up >> 5) & 31u)  - (int)((uq >> 5) & 31u);
            int db = (int)((up >> 10) & 31u) - (int)((uq >> 10) & 31u);
            float rgb = sqrtf((float)(dr * dr + dg * dg + db * db)) * RGBNORM5;
            float wv = (0.8f * euc + 0.2f * rgb) * INVQS2;
            // gather from LDS: two aligned b128 reads
            uint4 A  = zA[qv];
            uint4 Bv = zB[qv];
            const uint4* zc = (const uint4*)(&z1q[px][0]);   // uniform -> broadcast
            uint4 u0 = zc[0];
            uint4 u1 = zc[1];
            int di = 0;
            di = dot8(A.x,  u0.x, di);
            di = dot8(A.y,  u0.y, di);
            di = dot8(A.z,  u0.z, di);
            di = dot8(A.w,  u0.w, di);
            di = dot8(Bv.x, u1.x, di);
            di = dot8(Bv.y, u1.y, di);
            di = dot8(Bv.z, u1.z, di);
            di = dot8(Bv.w, u1.w, di);
            acc += fminf(fabsf((float)di * wv), 1.0f);
        }
    }
    atomicAdd(&partial2[((size_t)b * NGRP + ((blockIdx.x & 63) >> 2)) * NEG + k], acc);
}

// Merged stage-2 + final with shfl wave reductions.
__global__ __launch_bounds__(256) void k_reduce2f(const float* __restrict__ partial2,
                                                  const float* __restrict__ n1map,
                                                  float* __restrict__ out) {
    __shared__ float xw[3][4];
    int t = threadIdx.x;
    int lane = t & 63;
    int wid  = t >> 6;
    float bsum = 0.f, s0sum = 0.f, snegsum = 0.f;
    for (int b = 0; b < B; ++b) {
        float s = 0.f;
#pragma unroll
        for (int g = 0; g < NGRP; ++g)
            s += partial2[((size_t)b * NGRP + g) * NEG + t];
        float sneg = s * (1.0f / HW) * 0.5f;               // / HW / TEMPERATURE
        float l1m  = fmaxf(logf(1.0f - sneg), -100.0f);
        float ss = 0.f;
#pragma unroll
        for (int j = 0; j < HW / 256; ++j) {
            float n1 = n1map[b * HW + j * 256 + t];
            float n1sq = n1 * n1;
            ss += fminf(n1sq / fmaxf(n1sq, 1e-8f), 1.0f);
        }
        float r0 = sneg, r1 = l1m, r2 = ss;
#pragma unroll
        for (int o = 1; o < 64; o <<= 1) {
            r0 += __shfl_xor(r0, o);
            r1 += __shfl_xor(r1, o);
            r2 += __shfl_xor(r2, o);
        }
        if (lane == 0) { xw[0][wid] = r0; xw[1][wid] = r1; xw[2][wid] = r2; }
        __syncthreads();
        if (t == 0) {
            float sn = xw[0][0] + xw[0][1] + xw[0][2] + xw[0][3];
            float lm = xw[1][0] + xw[1][1] + xw[1][2] + xw[1][3];
            float sv = xw[2][0] + xw[2][1] + xw[2][2] + xw[2][3];
            float s0 = sv * (1.0f / HW);
            bsum    += -(fmaxf(logf(s0), -100.0f) + lm) * (1.0f / (NEG + 1));
            s0sum   += s0;
            snegsum += sn;
        }
        __syncthreads();
    }
    if (t == 0) {
        out[0] = bsum * 0.25f;                              // mean bce
        out[1] = s0sum * 0.25f;                             // sim_all[0] / B
        out[2] = snegsum * (1.0f / NEG) * 2.0f * 0.25f;     // sum/NEG*TEMP/B
    }
}

extern "C" void kernel_launch(void* const* d_in, const int* in_sizes, int n_in,
                              void* d_out, int out_size, void* d_ws, size_t ws_size,
                              hipStream_t stream) {
    const float* v1   = (const float*)d_in[0];
    const float* v2   = (const float*)d_in[1];
    const float* img  = (const float*)d_in[2];
    const int*   negh = (const int*)d_in[3];
    const int*   negw = (const int*)d_in[4];
    float* out = (float*)d_out;
    float* ws  = (float*)d_ws;

    uchar*  z2Ag     = (uchar*)(ws + OFF_Z2A);
    uchar*  z2Bg     = (uchar*)(ws + OFF_Z2B);
    float*  n1map    = ws + OFF_N1MAP;
    ushort* img_u16  = (ushort*)(ws + OFF_IMGU16);
    float*  partial2 = ws + OFF_PART2;

    hipLaunchKernelGGL(k_prep, dim3(320), dim3(256), 0, stream,
                       v2, v1, img, z2Ag, z2Bg, n1map, img_u16, partial2);
    hipLaunchKernelGGL(k_main, dim3(NBLK), dim3(512), 0, stream,
                       v1, negh, negw, (const uint4*)z2Ag, (const uint4*)z2Bg,
                       n1map, img_u16, partial2);
    hipLaunchKernelGGL(k_reduce2f, dim3(1), dim3(256), 0, stream, partial2, n1map, out);
}

// Round 14
// 32.265 us; speedup vs baseline: 6.1931x; 1.1393x over previous
//
#include <hip/hip_runtime.h>
#include <math.h>

typedef unsigned short ushort;
typedef unsigned int uint;
typedef unsigned char uchar;

#define B 4
#define C 64
#define H 64
#define W 64
#define HW 4096
#define NEG 256
#define NGRP 16
#define PXB 64                   // pixels per k_main block
#define NBLK (B * HW / PXB)      // 256 blocks = 1 per CU

#define QS 7.49f
#define INVQS2 (1.0f / (QS * QS))
#define RGBNORM5 0.0186243f      // 1/(31*sqrt(3))

// ---------------- ws layout (float units) ----------------
// z2A    : [B][HW] uint4 (channels 0-31,  int4 packed)  = B*HW*4 floats
// z2B    : [B][HW] uint4 (channels 32-63, int4 packed)  = B*HW*4 floats
// n1map  : [B][HW]
// imgu16 : [HW] ushort RGB555 = HW/2 floats
// partial2:[B][NGRP][NEG]  (atomically accumulated; zeroed by k_prep)
#define OFF_Z2A    0
#define OFF_Z2B    (OFF_Z2A + B*HW*4)
#define OFF_N1MAP  (OFF_Z2B + B*HW*4)
#define OFF_IMGU16 (OFF_N1MAP + B*HW)
#define OFF_PART2  (OFF_IMGU16 + HW/2)

__device__ __forceinline__ int nib(uint u, int j) {
    return ((int)(u << (28 - 4 * j))) >> 28;
}
__device__ __forceinline__ int dot8(uint a, uint b, int c) {
#if __has_builtin(__builtin_amdgcn_sdot8)
    return __builtin_amdgcn_sdot8((int)a, (int)b, c, false);
#else
#pragma unroll
    for (int j = 0; j < 8; ++j) c += nib(a, j) * nib(b, j);
    return c;
#endif
}

// Combined prep: blocks [0,256) transpose+quantize z2 -> split int4 columns (A/B);
// blocks [256,320) do n1map + RGB555 img table + zero partial2.
__global__ __launch_bounds__(256) void k_prep(const float* __restrict__ v2,
                                              const float* __restrict__ v1,
                                              const float* __restrict__ img,
                                              uchar* __restrict__ z2Ag,
                                              uchar* __restrict__ z2Bg,
                                              float* __restrict__ n1map,
                                              ushort* __restrict__ img_u16,
                                              float* __restrict__ partial2) {
    int t = threadIdx.x;
    if (blockIdx.x < 256) {
        __shared__ float tile[64][65];
        __shared__ float npart[4][64];
        __shared__ float ninv[64];
        int b  = blockIdx.x >> 6;
        int q0 = (blockIdx.x & 63) * 64;
        int qq = t & 63;
        int cg = t >> 6;
        const float* src = v2 + (size_t)b * C * HW;
        float acc = 0.f;
#pragma unroll
        for (int r = 0; r < 16; ++r) {
            int c = cg * 16 + r;
            float v = src[(size_t)c * HW + q0 + qq];
            tile[c][qq] = v;
            acc += v * v;
        }
        npart[cg][qq] = acc;
        __syncthreads();
        if (t < 64) {
            float s = npart[0][t] + npart[1][t] + npart[2][t] + npart[3][t];
            ninv[t] = QS / fmaxf(sqrtf(s), 1e-8f);
        }
        __syncthreads();
        int qw   = t >> 2;
        int quad = t & 3;
        int c0   = quad * 16;
        float inv = ninv[qw];
        uint u0 = 0, u1 = 0;
#pragma unroll
        for (int j = 0; j < 8; ++j) {
            int x0 = (int)rintf(tile[c0 + j][qw] * inv);
            int x1 = (int)rintf(tile[c0 + 8 + j][qw] * inv);
            u0 |= (uint)(x0 & 0xF) << (4 * j);
            u1 |= (uint)(x1 & 0xF) << (4 * j);
        }
        size_t col = (size_t)b * HW + q0 + qw;
        uint2 val = make_uint2(u0, u1);
        if (quad < 2) *(uint2*)(z2Ag + col * 16 + quad * 8)       = val;
        else          *(uint2*)(z2Bg + col * 16 + (quad - 2) * 8) = val;
    } else {
        int bid = blockIdx.x - 256;          // 0..63
        int b = bid >> 4;
        int q = (bid & 15) * 256 + t;
        partial2[bid * 256 + t] = 0.f;       // 64*256 == B*NGRP*NEG
        const float* src = v1 + (size_t)b * C * HW + q;
        float acc = 0.f;
#pragma unroll 8
        for (int c = 0; c < C; ++c) {
            float v = src[(size_t)c * HW];
            acc += v * v;
        }
        n1map[b * HW + q] = sqrtf(acc);
        if (b == 0) {
            uint r  = (uint)rintf(img[q] * 31.f);
            uint g  = (uint)rintf(img[HW + q] * 31.f);
            uint bl = (uint)rintf(img[2 * HW + q] * 31.f);
            img_u16[q] = (ushort)(r | (g << 5) | (bl << 10));
        }
    }
}

// Main: 256 blocks x 1024 threads (16 waves/CU). Whole-item z2 (128 KB int4, A/B
// split) + img table in LDS; thread = (k, px-quarter), 16 px each; all gathers LDS.
__global__ __launch_bounds__(1024) void k_main(const float* __restrict__ v1,
                                               const int* __restrict__ negh,
                                               const int* __restrict__ negw,
                                               const uint4* __restrict__ z2Ag,
                                               const uint4* __restrict__ z2Bg,
                                               const float* __restrict__ n1map,
                                               const ushort* __restrict__ img_u16,
                                               float* __restrict__ partial2) {
    __shared__ uint4 zA[HW];                // 64 KB: channels 0-31 per column
    __shared__ uint4 zB[HW];                // 64 KB: channels 32-63 per column
    __shared__ ushort imgu[HW];             // 8 KB RGB555
    __shared__ uint z1q[PXB][8];            // 2 KB int4-packed z1 columns
    int b  = blockIdx.x >> 6;
    int p0 = (blockIdx.x & 63) * PXB;
    int t  = threadIdx.x;

    {   // stage whole-item z2 (A/B) + img table, fully coalesced
        const uint4* gA = z2Ag + (size_t)b * HW;
        const uint4* gB = z2Bg + (size_t)b * HW;
#pragma unroll
        for (int i = 0; i < 4; ++i) {
            zA[i * 1024 + t] = gA[i * 1024 + t];
            zB[i * 1024 + t] = gB[i * 1024 + t];
        }
        if (t < 512) ((uint4*)imgu)[t] = ((const uint4*)img_u16)[t];
    }
    if (t < 512) {   // stage z1 columns, normalized xQS -> int4 packed (64 px x 8)
        int px = t >> 3;
        int ui = t & 7;
        const float* srcb = v1 + (size_t)b * C * HW + p0 + px;
        float inv = QS / fmaxf(n1map[b * HW + p0 + px], 1e-8f);
        uint u = 0;
#pragma unroll
        for (int j = 0; j < 8; ++j) {
            int x = (int)rintf(srcb[(size_t)(8 * ui + j) * HW] * inv);
            u |= (uint)(x & 0xF) << (4 * j);
        }
        z1q[px][ui] = u;
    }
    __syncthreads();

    const float inv_max_euc = 1.0f / sqrtf((float)((H - 1) * (H - 1) + (W - 1) * (W - 1)));
    int k       = t & 255;
    int quarter = t >> 8;                  // 0..3
    int pbase   = p0 + quarter * 16;
    const int* nh = negh + ((size_t)b * HW + pbase) * NEG + k;
    const int* nw = negw + ((size_t)b * HW + pbase) * NEG + k;

    float acc = 0.f;
#pragma unroll 2
    for (int j0 = 0; j0 < 16; j0 += 8) {
        int ihv[8], iwv[8];
#pragma unroll
        for (int j = 0; j < 8; ++j) {
            ihv[j] = nh[(j0 + j) * NEG];
            iwv[j] = nw[(j0 + j) * NEG];
        }
#pragma unroll
        for (int j = 0; j < 8; ++j) {
            int px = quarter * 16 + j0 + j;
            int p  = pbase + j0 + j;
            int ih = ihv[j], iw = iwv[j];
            int qv = (ih << 6) + iw;
            // weight
            float dh = (float)(p >> 6) - (float)ih;
            float dw = (float)(p & 63) - (float)iw;
            float euc = sqrtf(dh * dh + dw * dw) * inv_max_euc;
            uint up = imgu[p];                 // wave-uniform -> broadcast
            uint uq = imgu[qv];                // scattered LDS u16
            int dr = (int)(up & 31u)         - (int)(uq & 31u);
            int dg = (int)((up >> 5) & 31u)  - (int)((uq >> 5) & 31u);
            int db = (int)((up >> 10) & 31u) - (int)((uq >> 10) & 31u);
            float rgb = sqrtf((float)(dr * dr + dg * dg + db * db)) * RGBNORM5;
            float wv = (0.8f * euc + 0.2f * rgb) * INVQS2;
            // gather from LDS: two aligned b128 reads
            uint4 A  = zA[qv];
            uint4 Bv = zB[qv];
            const uint4* zc = (const uint4*)(&z1q[px][0]);   // uniform -> broadcast
            uint4 u0 = zc[0];
            uint4 u1 = zc[1];
            int di = 0;
            di = dot8(A.x,  u0.x, di);
            di = dot8(A.y,  u0.y, di);
            di = dot8(A.z,  u0.z, di);
            di = dot8(A.w,  u0.w, di);
            di = dot8(Bv.x, u1.x, di);
            di = dot8(Bv.y, u1.y, di);
            di = dot8(Bv.z, u1.z, di);
            di = dot8(Bv.w, u1.w, di);
            acc += fminf(fabsf((float)di * wv), 1.0f);
        }
    }
    atomicAdd(&partial2[((size_t)b * NGRP + ((blockIdx.x & 63) >> 2)) * NEG + k], acc);
}

// Merged stage-2 + final with shfl wave reductions.
__global__ __launch_bounds__(256) void k_reduce2f(const float* __restrict__ partial2,
                                                  const float* __restrict__ n1map,
                                                  float* __restrict__ out) {
    __shared__ float xw[3][4];
    int t = threadIdx.x;
    int lane = t & 63;
    int wid  = t >> 6;
    float bsum = 0.f, s0sum = 0.f, snegsum = 0.f;
    for (int b = 0; b < B; ++b) {
        float s = 0.f;
#pragma unroll
        for (int g = 0; g < NGRP; ++g)
            s += partial2[((size_t)b * NGRP + g) * NEG + t];
        float sneg = s * (1.0f / HW) * 0.5f;               // / HW / TEMPERATURE
        float l1m  = fmaxf(logf(1.0f - sneg), -100.0f);
        float ss = 0.f;
#pragma unroll
        for (int j = 0; j < HW / 256; ++j) {
            float n1 = n1map[b * HW + j * 256 + t];
            float n1sq = n1 * n1;
            ss += fminf(n1sq / fmaxf(n1sq, 1e-8f), 1.0f);
        }
        float r0 = sneg, r1 = l1m, r2 = ss;
#pragma unroll
        for (int o = 1; o < 64; o <<= 1) {
            r0 += __shfl_xor(r0, o);
            r1 += __shfl_xor(r1, o);
            r2 += __shfl_xor(r2, o);
        }
        if (lane == 0) { xw[0][wid] = r0; xw[1][wid] = r1; xw[2][wid] = r2; }
        __syncthreads();
        if (t == 0) {
            float sn = xw[0][0] + xw[0][1] + xw[0][2] + xw[0][3];
            float lm = xw[1][0] + xw[1][1] + xw[1][2] + xw[1][3];
            float sv = xw[2][0] + xw[2][1] + xw[2][2] + xw[2][3];
            float s0 = sv * (1.0f / HW);
            bsum    += -(fmaxf(logf(s0), -100.0f) + lm) * (1.0f / (NEG + 1));
            s0sum   += s0;
            snegsum += sn;
        }
        __syncthreads();
    }
    if (t == 0) {
        out[0] = bsum * 0.25f;                              // mean bce
        out[1] = s0sum * 0.25f;                             // sim_all[0] / B
        out[2] = snegsum * (1.0f / NEG) * 2.0f * 0.25f;     // sum/NEG*TEMP/B
    }
}

extern "C" void kernel_launch(void* const* d_in, const int* in_sizes, int n_in,
                              void* d_out, int out_size, void* d_ws, size_t ws_size,
                              hipStream_t stream) {
    const float* v1   = (const float*)d_in[0];
    const float* v2   = (const float*)d_in[1];
    const float* img  = (const float*)d_in[2];
    const int*   negh = (const int*)d_in[3];
    const int*   negw = (const int*)d_in[4];
    float* out = (float*)d_out;
    float* ws  = (float*)d_ws;

    uchar*  z2Ag     = (uchar*)(ws + OFF_Z2A);
    uchar*  z2Bg     = (uchar*)(ws + OFF_Z2B);
    float*  n1map    = ws + OFF_N1MAP;
    ushort* img_u16  = (ushort*)(ws + OFF_IMGU16);
    float*  partial2 = ws + OFF_PART2;

    hipLaunchKernelGGL(k_prep, dim3(320), dim3(256), 0, stream,
                       v2, v1, img, z2Ag, z2Bg, n1map, img_u16, partial2);
    hipLaunchKernelGGL(k_main, dim3(NBLK), dim3(1024), 0, stream,
                       v1, negh, negw, (const uint4*)z2Ag, (const uint4*)z2Bg,
                       n1map, img_u16, partial2);
    hipLaunchKernelGGL(k_reduce2f, dim3(1), dim3(256), 0, stream, partial2, n1map, out);
}